// Round 16
// baseline (111.794 us; speedup 1.0000x reference)
//
#include <hip/hip_runtime.h>
#include <cstdint>

#define DEV static __device__ __forceinline__

typedef __attribute__((__ext_vector_type__(8))) __bf16 bf16x8;
typedef __attribute__((__ext_vector_type__(4))) float f32x4;

static constexpr int Bc = 16, Sc = 2048, Dc = 1024;

DEV unsigned short f2bf(float x) {
  unsigned int u = __float_as_uint(x);
  unsigned int r = (u + 0x7fffu + ((u >> 16) & 1u)) >> 16;
  return (unsigned short)r;
}
DEV unsigned int pack2(float a, float b) {
  return (unsigned int)f2bf(a) | ((unsigned int)f2bf(b) << 16);
}
DEV float tanh_fast(float x) {
  return 1.f - 2.f / (__expf(2.f * x) + 1.f);
}
DEV void gload16(const void* g, void* l) {
  __builtin_amdgcn_global_load_lds(
      (const __attribute__((address_space(1))) unsigned int*)g,
      (__attribute__((address_space(3))) unsigned int*)l, 16, 0, 0);
}

// ---- kernel 1: FUSED prep (one launch, independent work co-scheduled):
//   blocks [0,2048):    enc fp32->bf16 (length-skipped) -- the long pole
//   blocks [2048,3072): hidproj e = bx-2048 (+ worklist in block 2048)
//   blocks [3072,3584): We fp32->bf16
__global__ __launch_bounds__(256) void k_prep(const float* __restrict__ enc,
                                              const float* __restrict__ hidden,
                                              const float* __restrict__ W,
                                              const float* __restrict__ bias,
                                              const int* __restrict__ lengths,
                                              unsigned short* __restrict__ ebf,
                                              unsigned short* __restrict__ webf,
                                              float* __restrict__ hp,
                                              int* __restrict__ wl) {
  int bx = blockIdx.x;
  int t = threadIdx.x;
  if (bx < 2048) {
    int team = t >> 7, lane = t & 127;
    int r0 = bx * 16;
    int b = r0 >> 11;
    int len = lengths[b];
    for (int rr = team; rr < 16; rr += 2) {
      int s = (r0 + rr) & 2047;
      if (s >= len) continue;
      const float* src = enc + (size_t)(r0 + rr) * Dc + lane * 8;
      unsigned short* dst = ebf + (size_t)(r0 + rr) * Dc + lane * 8;
      float4 f0 = *(const float4*)src;
      float4 f1 = *(const float4*)(src + 4);
      uint4 o;
      o.x = pack2(f0.x, f0.y);
      o.y = pack2(f0.z, f0.w);
      o.z = pack2(f1.x, f1.y);
      o.w = pack2(f1.z, f1.w);
      *(uint4*)dst = o;
    }
  } else if (bx < 3072) {
    int e = bx - 2048;
    if (e == 0) {
      int sblk = t >> 4, b = t & 15;  // t = sblk*16 + b
      int active = (sblk * 128 < lengths[b]) ? 1 : 0;
      unsigned long long mask = __ballot(active);
      int lane = t & 63, wid = t >> 6;
      int prefix = __popcll(mask & ((1ull << lane) - 1ull));
      __shared__ int woff[4];
      if (lane == 0) woff[wid] = __popcll(mask);
      __syncthreads();
      int base = 0;
      for (int i = 0; i < wid; i++) base += woff[i];
      if (active) wl[1 + base + prefix] = (b << 8) | sblk;
      if (t == 0) wl[0] = woff[0] + woff[1] + woff[2] + woff[3];
    }
    __shared__ float wrow[Dc];
    for (int i = t; i < Dc; i += 256) wrow[i] = W[(size_t)e * 2048 + i];
    __syncthreads();
    int w = t >> 6, lane = t & 63;
    float bv = bias[e];
    for (int bi = w; bi < Bc; bi += 4) {
      float s = 0.f;
      const float* hrow = hidden + (size_t)bi * Dc;
      for (int d = lane; d < Dc; d += 64) s += hrow[d] * wrow[d];
      for (int m = 1; m < 64; m <<= 1) s += __shfl_xor(s, m);
      if (lane == 0) hp[(size_t)bi * Dc + e] = s + bv;
    }
  } else {
    int i = ((bx - 3072) * 256 + t) * 8;
    int e = i >> 10, d = i & 1023;
    const float* p = W + (size_t)e * 2048 + 1024 + d;
    float4 f0 = *(const float4*)p;
    float4 f1 = *(const float4*)(p + 4);
    uint4 o;
    o.x = pack2(f0.x, f0.y);
    o.y = pack2(f0.z, f0.w);
    o.z = pack2(f1.x, f1.y);
    o.w = pack2(f1.z, f1.w);
    *(uint4*)(webf + i) = o;
  }
}

// ---- kernel 2: scores GEMM, BIG-TILE variant: block = 128M x 256E, 4 waves,
// each wave owns 128x64 (acc[8][4], 32 MFMA per K-step). Halves total
// phase-slots (544 blocks x 32 iters vs 1088 x 32) at 2x FLOP per slot --
// the lever implied by 15 rounds of "slot cost is ~fixed".
// Keeps: counted vmcnt (6 loads/stage, wait vmcnt(6)), T2 both-sides LDS
// swizzle (same per-thread pre-swizzle algebra for A and B regions),
// T5 setprio, worklist, g=bx&255 / et=bx>>8 (XCD affinity: bx%8=g%8).
// Determinism: each wave stores its row-partials to its own sc4[w] slice
// (plain stores), then t<128 sums the 4 slices in fixed order.
__global__ __launch_bounds__(256) void k_scores(const unsigned short* __restrict__ Ae,
                                                const unsigned short* __restrict__ We,
                                                const float* __restrict__ hp,
                                                const float* __restrict__ v,
                                                const int* __restrict__ wl,
                                                float* __restrict__ pscores) {
  int g = blockIdx.x & 255;
  int et = blockIdx.x >> 8;  // 0..3
  if (g >= wl[0]) return;
  int pk = wl[1 + g];
  int b = pk >> 8, sblk = pk & 255;
  int s0 = sblk * 128;
  int m0 = b * Sc + s0;
  int e0 = et * 256;

  __shared__ unsigned short As0[128 * 32];   // 8 KB
  __shared__ unsigned short As1[128 * 32];   // 8 KB
  __shared__ unsigned short Bs0[256 * 32];   // 16 KB
  __shared__ unsigned short Bs1[256 * 32];   // 16 KB
  float* sc4 = (float*)As0;  // [4][128] partials; As0 dead in epilogue

  int t = threadIdx.x;
  int w = t >> 6, lane = t & 63;

  f32x4 acc[8][4] = {};

  // T2 pre-swizzle (identical algebra to round 12, applied to both regions):
  // octet o=t>>3 covers row-pair o; slot q=t&7 holds global slot g8=q^(o&7):
  // source row 2o+(g8>>2), chunk g8&3. Each extra stage call = +64 rows
  // (+32 pairs, (o+32)&7 invariant -> same per-thread offset).
  {
    int o = t >> 3, q = t & 7;
    int g8 = q ^ (o & 7);
    int srow = 2 * o + (g8 >> 2);
    int scol = (g8 & 3) * 8;
    Ae += (size_t)(m0 + srow) * Dc + scol;
    We += (size_t)(e0 + srow) * Dc + scol;
  }
  const unsigned short* ga0 = Ae;
  const unsigned short* gb0 = We;

  // Read-side swizzle (per-lane constants).
  int posw = (((lane & 1) << 2) + (lane >> 4)) ^ (((lane & 15) >> 1) & 7);
  int aoff = ((lane & 15) >> 1) * 64 + posw * 8;             // + m*512
  int boff = (w * 32 + ((lane & 15) >> 1)) * 64 + posw * 8;  // + n*512

  // 6 VMEM instructions per wave per stage: A 8KB (2 calls) + B 16KB (4).
  auto stage = [&](int k0, unsigned short* A, unsigned short* B) {
    gload16(ga0 + k0, A + w * 512);
    gload16(ga0 + k0 + 64 * Dc, A + 2048 + w * 512);
    gload16(gb0 + k0, B + w * 512);
    gload16(gb0 + k0 + 64 * Dc, B + 2048 + w * 512);
    gload16(gb0 + k0 + 128 * Dc, B + 4096 + w * 512);
    gload16(gb0 + k0 + 192 * Dc, B + 6144 + w * 512);
  };
  auto compute = [&](const unsigned short* A, const unsigned short* B) {
    bf16x8 af[8], bfr[4];
#pragma unroll
    for (int m = 0; m < 8; m++)
      af[m] = __builtin_bit_cast(bf16x8, *(const uint4*)(A + aoff + m * 512));
#pragma unroll
    for (int n = 0; n < 4; n++)
      bfr[n] = __builtin_bit_cast(bf16x8, *(const uint4*)(B + boff + n * 512));
    __builtin_amdgcn_s_setprio(1);
#pragma unroll
    for (int m = 0; m < 8; m++)
#pragma unroll
      for (int n = 0; n < 4; n++)
        acc[m][n] = __builtin_amdgcn_mfma_f32_16x16x32_bf16(af[m], bfr[n], acc[m][n], 0, 0, 0);
    __builtin_amdgcn_s_setprio(0);
  };

  stage(0, As0, Bs0);  // 6 outstanding

#pragma unroll 1
  for (int i2 = 0; i2 < 15; ++i2) {
    stage((2 * i2 + 1) * 32, As1, Bs1);                // 12 outstanding
    asm volatile("s_waitcnt vmcnt(6)" ::: "memory");   // even tile landed
    __builtin_amdgcn_sched_barrier(0);
    __builtin_amdgcn_s_barrier();
    __builtin_amdgcn_sched_barrier(0);
    compute(As0, Bs0);
    __builtin_amdgcn_sched_barrier(0);
    __builtin_amdgcn_s_barrier();
    stage((2 * i2 + 2) * 32, As0, Bs0);
    asm volatile("s_waitcnt vmcnt(6)" ::: "memory");
    __builtin_amdgcn_sched_barrier(0);
    __builtin_amdgcn_s_barrier();
    __builtin_amdgcn_sched_barrier(0);
    compute(As1, Bs1);
    __builtin_amdgcn_sched_barrier(0);
    __builtin_amdgcn_s_barrier();
  }
  // tail: tile 30 in As0/Bs0; stage 31, compute both.
  stage(31 * 32, As1, Bs1);
  asm volatile("s_waitcnt vmcnt(6)" ::: "memory");
  __builtin_amdgcn_sched_barrier(0);
  __builtin_amdgcn_s_barrier();
  __builtin_amdgcn_sched_barrier(0);
  compute(As0, Bs0);
  __builtin_amdgcn_sched_barrier(0);
  __builtin_amdgcn_s_barrier();   // all waves done reading As0 -> sc4 safe
  asm volatile("s_waitcnt vmcnt(0)" ::: "memory");
  __builtin_amdgcn_sched_barrier(0);
  __builtin_amdgcn_s_barrier();
  __builtin_amdgcn_sched_barrier(0);
  compute(As1, Bs1);

  // epilogue: per-wave rowsum over its 64 e-cols of v[e]*tanh(acc+hp[e]).
  float hpv[4], vv[4];
#pragma unroll
  for (int n = 0; n < 4; n++) {
    int ec = w * 64 + n * 16 + (lane & 15);
    hpv[n] = hp[(size_t)b * Dc + e0 + ec];
    vv[n] = v[e0 + ec];
  }
  for (int m = 0; m < 8; m++) {
    float rs0 = 0.f, rs1 = 0.f, rs2 = 0.f, rs3 = 0.f;
#pragma unroll
    for (int n = 0; n < 4; n++) {
      f32x4 a = acc[m][n];
      rs0 += vv[n] * tanh_fast(a[0] + hpv[n]);
      rs1 += vv[n] * tanh_fast(a[1] + hpv[n]);
      rs2 += vv[n] * tanh_fast(a[2] + hpv[n]);
      rs3 += vv[n] * tanh_fast(a[3] + hpv[n]);
    }
    for (int mask = 1; mask < 16; mask <<= 1) {
      rs0 += __shfl_xor(rs0, mask);
      rs1 += __shfl_xor(rs1, mask);
      rs2 += __shfl_xor(rs2, mask);
      rs3 += __shfl_xor(rs3, mask);
    }
    if ((lane & 15) == 0) {  // each wave: exactly 1 writer/row, plain store
      int rbase = m * 16 + (lane >> 4) * 4;
      sc4[w * 128 + rbase + 0] = rs0;
      sc4[w * 128 + rbase + 1] = rs1;
      sc4[w * 128 + rbase + 2] = rs2;
      sc4[w * 128 + rbase + 3] = rs3;
    }
  }
  __syncthreads();
  if (t < 128)  // fixed summation order -> deterministic
    pscores[((size_t)et * Bc + b) * Sc + s0 + t] =
        sc4[t] + sc4[128 + t] + sc4[256 + t] + sc4[384 + t];
}

// ---- kernel 3: masked softmax over S per batch; sums 4 e-tile partials
__global__ __launch_bounds__(256) void k_softmax(const float* __restrict__ pscores,
                                                 const int* __restrict__ lengths,
                                                 float* __restrict__ attn) {
  int b = blockIdx.x, t = threadIdx.x;
  int len = lengths[b];
  float vals[8];
  float mx = -INFINITY;
  for (int i = 0; i < 8; i++) {
    int s = t + i * 256;
    float sc = 0.f;
    for (int p = 0; p < 4; p++) sc += pscores[((size_t)p * Bc + b) * Sc + s];
    sc = (s < len) ? sc : -INFINITY;
    vals[i] = sc;
    mx = fmaxf(mx, sc);
  }
  for (int m = 1; m < 64; m <<= 1) mx = fmaxf(mx, __shfl_xor(mx, m));
  __shared__ float rmax[4], rsum[4];
  int w = t >> 6, lane = t & 63;
  if (lane == 0) rmax[w] = mx;
  __syncthreads();
  mx = fmaxf(fmaxf(rmax[0], rmax[1]), fmaxf(rmax[2], rmax[3]));
  float sm = 0.f;
  for (int i = 0; i < 8; i++) {
    vals[i] = __expf(vals[i] - mx);
    sm += vals[i];
  }
  for (int m = 1; m < 64; m <<= 1) sm += __shfl_xor(sm, m);
  if (lane == 0) rsum[w] = sm;
  __syncthreads();
  sm = rsum[0] + rsum[1] + rsum[2] + rsum[3];
  float inv = 1.f / sm;
  for (int i = 0; i < 8; i++) attn[(size_t)b * Sc + t + i * 256] = vals[i] * inv;
}

// ---- kernel 4: context partials from bf16 enc, 64 splits of 32 rows.
__global__ __launch_bounds__(256) void k_ctx(const unsigned short* __restrict__ ebf,
                                             const float* __restrict__ attn,
                                             const int* __restrict__ lengths,
                                             float* __restrict__ pctx) {
  int b = blockIdx.x >> 6, sp = blockIdx.x & 63;
  int t = threadIdx.x;
  int d0 = t * 4;
  int sbeg = sp * 32;
  float* outp = pctx + ((size_t)sp * Bc + b) * Dc + d0;
  int len = lengths[b];
  if (sbeg >= len) {
    *(float4*)outp = make_float4(0.f, 0.f, 0.f, 0.f);
    return;
  }
  __shared__ float at_s[32];
  if (t < 32) at_s[t] = attn[(size_t)b * Sc + sbeg + t];
  __syncthreads();
  float4 a = make_float4(0.f, 0.f, 0.f, 0.f);
  const unsigned short* ebase = ebf + ((size_t)b * Sc + sbeg) * Dc + d0;
  int ns = min(32, len - sbeg);
  for (int i = 0; i < ns; i++) {
    float wt = at_s[i];
    uint2 u = *(const uint2*)(ebase + (size_t)i * Dc);
    a.x += wt * __uint_as_float(u.x << 16);
    a.y += wt * __uint_as_float(u.x & 0xffff0000u);
    a.z += wt * __uint_as_float(u.y << 16);
    a.w += wt * __uint_as_float(u.y & 0xffff0000u);
  }
  *(float4*)outp = a;
}

// ---- kernel 5: reduce 64 context partials -> out (B,1,D)
__global__ __launch_bounds__(256) void k_reduce(const float* __restrict__ pctx,
                                               float* __restrict__ out) {
  int i = blockIdx.x * 256 + threadIdx.x;
  int b = i >> 10, d = i & 1023;
  float s = 0.f;
  for (int p = 0; p < 64; p++) s += pctx[((size_t)p * Bc + b) * Dc + d];
  out[i] = s;
}

extern "C" void kernel_launch(void* const* d_in, const int* in_sizes, int n_in,
                              void* d_out, int out_size, void* d_ws, size_t ws_size,
                              hipStream_t stream) {
  const float* enc = (const float*)d_in[0];
  const float* hidden = (const float*)d_in[1];
  const int* lengths = (const int*)d_in[2];
  const float* W = (const float*)d_in[3];
  const float* bias = (const float*)d_in[4];
  const float* v = (const float*)d_in[5];
  float* out = (float*)d_out;

  char* ws = (char*)d_ws;
  unsigned short* ebf = (unsigned short*)ws;                // 64 MB
  unsigned short* webf = (unsigned short*)(ws + 67108864);  // 2 MB
  float* hp = (float*)(ws + 69206016);                      // 64 KB
  float* pscores = (float*)(ws + 69271552);                 // 512 KB (4 slices)
  float* attn = (float*)(ws + 70320128);                    // 128 KB
  float* pctx = (float*)(ws + 70451200);                    // 4 MB (64 splits)
  int* wl = (int*)(ws + 74645504);                          // worklist

  hipLaunchKernelGGL(k_prep, dim3(3584), dim3(256), 0, stream, enc, hidden, W, bias,
                     lengths, ebf, webf, hp, wl);
  hipLaunchKernelGGL(k_scores, dim3(1024), dim3(256), 0, stream, ebf, webf, hp, v,
                     wl, pscores);
  hipLaunchKernelGGL(k_softmax, dim3(16), dim3(256), 0, stream, pscores, lengths, attn);
  hipLaunchKernelGGL(k_ctx, dim3(1024), dim3(256), 0, stream, ebf, attn, lengths, pctx);
  hipLaunchKernelGGL(k_reduce, dim3(64), dim3(256), 0, stream, pctx, out);
}